// Round 9
// baseline (61.793 us; speedup 1.0000x reference)
//
#include <hip/hip_runtime.h>

// ESRNN Holt-Winters, B=65536 series, T=512, period M=12.
// R9: time-split for occupancy. 2048 blocks of 1 wave (2 waves/SIMD):
//   block 2p+0: outputs steps 0..255 for series [64p, 64p+64)
//   block 2p+1: carry-replays steps 0..255 (l,b,ring only; direct per-row x
//               reads, L3-co-resident with h=0's coalesced fetches), then
//               outputs steps 256..511 (ring phase 4 = 256%12, compile-time).
// Output pipeline per half: 5 x 48-step chunks + 16-step tail, single 16 KB
// in-place LDS buffer ([series][time-f4], 16B-slot XOR swizzle, all b128),
// depth-1 register prefetch, NT stores. 16 KB x 8 blocks/CU = 128 KB.

constexpr int SW     = 64;       // series per block (one wave)
constexpr int SROW   = 64;       // LDS row stride in floats (16 slots of 16B)
constexpr int PITCH4 = 512 / 4;  // global row pitch in float4 units (128)

typedef float f32x4 __attribute__((ext_vector_type(4)));

#define CBAR() asm volatile("" ::: "memory")   // compiler-only barrier

#define STEPM(XV, SH, SN, OV)                                              \
    do {                                                                   \
        const float s_h_ = ring[SH];                                       \
        const float q_   = (XV) * __builtin_amdgcn_rcpf(s_h_);             \
        const float lb_  = fmaf(b, phi, l);                                \
        const float ln_  = fmaf(alpha, q_, omal * lb_);                    \
        const float bphi_ = b * phi;                                       \
        const float bn_  = fmaf(beta, ln_ - l, ombe * bphi_);              \
        const float lb2_ = fmaf(bn_, phi, ln_);                            \
        const float sn_  = fmaf(gamma, (XV) * __builtin_amdgcn_rcpf(lb2_), \
                                omg * s_h_);                               \
        (OV) = lb2_ * ring[SN];                                            \
        ring[SH] = sn_;                                                    \
        l = ln_; b = bn_;                                                  \
    } while (0)

// carry-only step: same l/b/ring update, no output term
#define STEPC(XV, SH)                                                      \
    do {                                                                   \
        const float s_h_ = ring[SH];                                       \
        const float q_   = (XV) * __builtin_amdgcn_rcpf(s_h_);             \
        const float lb_  = fmaf(b, phi, l);                                \
        const float ln_  = fmaf(alpha, q_, omal * lb_);                    \
        const float bphi_ = b * phi;                                       \
        const float bn_  = fmaf(beta, ln_ - l, ombe * bphi_);              \
        const float lb2_ = fmaf(bn_, phi, ln_);                            \
        const float sn_  = fmaf(gamma, (XV) * __builtin_amdgcn_rcpf(lb2_), \
                                omg * s_h_);                               \
        ring[SH] = sn_;                                                    \
        l = ln_; b = bn_;                                                  \
    } while (0)

// One 256-step output half starting at ring phase P (P = S0 % 12).
// base4 = f4 offset of this half within the row (0 or 64).
template<int P>
__device__ __forceinline__ void half_pipeline(
    const f32x4* __restrict__ x4, f32x4* __restrict__ o4, int base4,
    int tid, int t7,
    const int (&gx)[12], const int (&lo)[12],
    const int (&gxT)[4], const int (&loT)[4],
    float& l, float& b, float (&ring)[12],
    float alpha, float beta, float phi, float gamma,
    float omal, float ombe, float omg,
    float* lds)
{
    f32x4 vx[12], vt[4];

    // prologue: load chunk 0 of this half
    #pragma unroll
    for (int m = 0; m < 12; ++m)
        vx[m] = x4[gx[m] + base4];

    #pragma unroll 1
    for (int k = 0; k < 5; ++k) {
        // 1. stage chunk k (12 x ds_write_b128; counted vmcnt waits on vx)
        #pragma unroll
        for (int m = 0; m < 12; ++m)
            *reinterpret_cast<f32x4*>(&lds[lo[m]]) = vx[m];
        CBAR();

        // 2. issue next chunk's loads (or the 16-step tail's)
        if (k < 4) {
            #pragma unroll
            for (int m = 0; m < 12; ++m)
                vx[m] = x4[gx[m] + base4 + (k + 1) * 12];
        } else {
            #pragma unroll
            for (int m = 0; m < 4; ++m)
                vt[m] = x4[gxT[m] + base4 + 60];
        }
        CBAR();

        // 3. compute 48 steps in place (chunk-start phase is P: 48%12==0)
        #pragma unroll
        for (int q = 0; q < 12; ++q) {
            const int sl = tid * SROW + ((q ^ t7) << 2);
            const f32x4 xq = *reinterpret_cast<const f32x4*>(&lds[sl]);
            f32x4 oq;
            STEPM(xq.x, (P + 4 * q + 0) % 12, (P + 4 * q + 1) % 12, oq.x);
            STEPM(xq.y, (P + 4 * q + 1) % 12, (P + 4 * q + 2) % 12, oq.y);
            STEPM(xq.z, (P + 4 * q + 2) % 12, (P + 4 * q + 3) % 12, oq.z);
            STEPM(xq.w, (P + 4 * q + 3) % 12, (P + 4 * q + 4) % 12, oq.w);
            *reinterpret_cast<f32x4*>(&lds[sl]) = oq;
        }
        CBAR();

        // 4. transpose-read + NT store
        #pragma unroll
        for (int m = 0; m < 12; ++m) {
            const f32x4 o = *reinterpret_cast<const f32x4*>(&lds[lo[m]]);
            __builtin_nontemporal_store(o, &o4[gx[m] + base4 + k * 12]);
        }
        CBAR();
    }

    // ---- 16-step tail (local steps 240..255; phase still P) ----
    #pragma unroll
    for (int m = 0; m < 4; ++m)
        *reinterpret_cast<f32x4*>(&lds[loT[m]]) = vt[m];
    CBAR();
    #pragma unroll
    for (int q = 0; q < 4; ++q) {
        const int sl = tid * SROW + ((q ^ t7) << 2);
        const f32x4 xq = *reinterpret_cast<const f32x4*>(&lds[sl]);
        f32x4 oq;
        STEPM(xq.x, (P + 4 * q + 0) % 12, (P + 4 * q + 1) % 12, oq.x);
        STEPM(xq.y, (P + 4 * q + 1) % 12, (P + 4 * q + 2) % 12, oq.y);
        STEPM(xq.z, (P + 4 * q + 2) % 12, (P + 4 * q + 3) % 12, oq.z);
        STEPM(xq.w, (P + 4 * q + 3) % 12, (P + 4 * q + 4) % 12, oq.w);
        *reinterpret_cast<f32x4*>(&lds[sl]) = oq;
    }
    CBAR();
    #pragma unroll
    for (int m = 0; m < 4; ++m) {
        const f32x4 o = *reinterpret_cast<const f32x4*>(&lds[loT[m]]);
        __builtin_nontemporal_store(o, &o4[gxT[m] + base4 + 60]);
    }
}

__global__ __launch_bounds__(64, 2) void esrnn_kernel(
    const float* __restrict__ x,
    const float* __restrict__ p_alpha,
    const float* __restrict__ p_beta,
    const float* __restrict__ p_phi,
    const float* __restrict__ p_gamma,
    const float* __restrict__ l0,
    const float* __restrict__ b0,
    const float* __restrict__ s0,
    float* __restrict__ out)
{
    const int tid = threadIdx.x;
    const int t7  = tid & 7;
    const int g   = blockIdx.x;
    const int pair = g >> 1;
    const int h    = g & 1;
    const int series0 = pair * SW;
    const int i = series0 + tid;

    __shared__ __align__(16) float lds[SW * SROW];   // 16 KB, in-place

    const float alpha = p_alpha[0];
    const float beta  = p_beta[0];
    const float phi   = p_phi[0];
    const float gamma = p_gamma[0];
    const float omal  = 1.0f - alpha;
    const float ombe  = 1.0f - beta;
    const float omg   = 1.0f - gamma;

    float l = l0[i];
    float b = b0[i];

    float ring[12];
    {
        const f32x4* s04 = reinterpret_cast<const f32x4*>(s0 + (size_t)i * 12);
        f32x4 sa = s04[0], sb = s04[1], sc = s04[2];
        ring[0] = sa.x; ring[1] = sa.y; ring[2]  = sa.z; ring[3]  = sa.w;
        ring[4] = sb.x; ring[5] = sb.y; ring[6]  = sb.z; ring[7]  = sb.w;
        ring[8] = sc.x; ring[9] = sc.y; ring[10] = sc.z; ring[11] = sc.w;
    }

    // tile maps. 48-chunk: flat f4 index f = tid + 64*m over a 64x12 f4 tile
    // -> series row r = f/12, time f4-col q = f%12. Swizzled LDS offset:
    // r*SROW + ((q ^ (r&7)) << 2)  (fits: q<12 -> swizzled slot < 16).
    int gx[12], lo[12];
    #pragma unroll
    for (int m = 0; m < 12; ++m) {
        const int f = tid + SW * m;
        const int r = f / 12;
        const int q = f - 12 * r;
        gx[m] = r * PITCH4 + q;
        lo[m] = r * SROW + ((q ^ (r & 7)) << 2);
    }
    // 16-step tail: 64x4 f4 tile -> r = f>>2, q = f&3 (slot < 8).
    int gxT[4], loT[4];
    #pragma unroll
    for (int m = 0; m < 4; ++m) {
        const int f = tid + SW * m;
        const int r = f >> 2;
        const int q = f & 3;
        gxT[m] = r * PITCH4 + q;
        loT[m] = r * SROW + ((q ^ (r & 7)) << 2);
    }

    const f32x4* x4 = reinterpret_cast<const f32x4*>(x) + (size_t)series0 * PITCH4;
    f32x4*       o4 = reinterpret_cast<f32x4*>(out)     + (size_t)series0 * PITCH4;

    if (h == 0) {
        // steps 0..255 with output
        half_pipeline<0>(x4, o4, 0, tid, t7, gx, lo, gxT, loT,
                         l, b, ring, alpha, beta, phi, gamma,
                         omal, ombe, omg, lds);
    } else {
        // carry-replay steps 0..255: direct reads of this thread's own row
        // (first touch of x[0:256] -> fills L3 for the sibling h=0 block).
        const f32x4* xr = reinterpret_cast<const f32x4*>(x) + (size_t)i * PITCH4;

        #pragma unroll 1
        for (int cg = 0; cg < 5; ++cg) {        // 5 x 48 steps
            f32x4 va[12];
            #pragma unroll
            for (int j = 0; j < 12; ++j)
                va[j] = xr[cg * 12 + j];
            #pragma unroll
            for (int j = 0; j < 12; ++j) {
                STEPC(va[j].x, (4 * j + 0) % 12);
                STEPC(va[j].y, (4 * j + 1) % 12);
                STEPC(va[j].z, (4 * j + 2) % 12);
                STEPC(va[j].w, (4 * j + 3) % 12);
            }
        }
        {   // 16-step carry tail (steps 240..255, phase 0)
            f32x4 vt4[4];
            #pragma unroll
            for (int j = 0; j < 4; ++j)
                vt4[j] = xr[60 + j];
            #pragma unroll
            for (int j = 0; j < 4; ++j) {
                STEPC(vt4[j].x, (4 * j + 0) % 12);
                STEPC(vt4[j].y, (4 * j + 1) % 12);
                STEPC(vt4[j].z, (4 * j + 2) % 12);
                STEPC(vt4[j].w, (4 * j + 3) % 12);
            }
        }
        // steps 256..511 with output; ring phase 256 % 12 == 4
        half_pipeline<4>(x4, o4, 64, tid, t7, gx, lo, gxT, loT,
                         l, b, ring, alpha, beta, phi, gamma,
                         omal, ombe, omg, lds);
    }
}

extern "C" void kernel_launch(void* const* d_in, const int* in_sizes, int n_in,
                              void* d_out, int out_size, void* d_ws, size_t ws_size,
                              hipStream_t stream)
{
    const float* x       = (const float*)d_in[0];
    const float* p_alpha = (const float*)d_in[1];
    const float* p_beta  = (const float*)d_in[2];
    const float* p_phi   = (const float*)d_in[3];
    const float* p_gamma = (const float*)d_in[4];
    const float* l0      = (const float*)d_in[5];
    const float* b0      = (const float*)d_in[6];
    const float* s0      = (const float*)d_in[7];
    float* out = (float*)d_out;

    const int B = in_sizes[5];              // l0 has B elements
    const int grid = (B / SW) * 2;          // 2048 blocks of 64 threads

    esrnn_kernel<<<grid, SW, 0, stream>>>(x, p_alpha, p_beta, p_phi, p_gamma,
                                          l0, b0, s0, out);
}

// Round 10
// 57.592 us; speedup vs baseline: 1.0729x; 1.0729x over previous
//
#include <hip/hip_runtime.h>

// ESRNN Holt-Winters, B=65536 series, T=512, period M=12.
// R10 = R6 EXACTLY (best known: 46.6 us) with a single A/B variable flipped:
// regular global stores instead of __builtin_nontemporal_store. Isolates the
// NT hint's effect on L3 retention of x (FETCH_SIZE) vs write-path speed.
// Everything else identical: one wave/block, TC=48 chunks, all-b128 LDS with
// 16B-slot XOR swizzle, depth-2 register prefetch, compiler-only fences.

constexpr int TT     = 512;     // timesteps
constexpr int TC     = 48;      // chunk steps
constexpr int NCH    = 10;      // full chunks (480 steps)
constexpr int SW     = 64;      // series per block (one wave)
constexpr int SROW   = 64;      // LDS row stride in floats (16 slots of 16B)
constexpr int PITCH4 = TT / 4;  // global row pitch in float4 units (128)

typedef float f32x4 __attribute__((ext_vector_type(4)));

#define CBAR() asm volatile("" ::: "memory")   // compiler-only barrier

#define STEPM(XV, SH, SN, OV)                                              \
    do {                                                                   \
        const float s_h_ = ring[SH];                                       \
        const float q_   = (XV) * __builtin_amdgcn_rcpf(s_h_);             \
        const float lb_  = fmaf(b, phi, l);                                \
        const float ln_  = fmaf(alpha, q_, omal * lb_);                    \
        const float bphi_ = b * phi;                                       \
        const float bn_  = fmaf(beta, ln_ - l, ombe * bphi_);              \
        const float lb2_ = fmaf(bn_, phi, ln_);                            \
        const float sn_  = fmaf(gamma, (XV) * __builtin_amdgcn_rcpf(lb2_), \
                                omg * s_h_);                               \
        (OV) = lb2_ * ring[SN];                                            \
        ring[SH] = sn_;                                                    \
        l = ln_; b = bn_;                                                  \
    } while (0)

__global__ __launch_bounds__(64) void esrnn_kernel(
    const float* __restrict__ x,
    const float* __restrict__ p_alpha,
    const float* __restrict__ p_beta,
    const float* __restrict__ p_phi,
    const float* __restrict__ p_gamma,
    const float* __restrict__ l0,
    const float* __restrict__ b0,
    const float* __restrict__ s0,
    float* __restrict__ out)
{
    const int tid = threadIdx.x;
    const int t7  = tid & 7;
    const int series0 = blockIdx.x * SW;
    const int i = series0 + tid;

    __shared__ __align__(16) float lds_x[SW * SROW];   // 16 KB
    __shared__ __align__(16) float lds_o[SW * SROW];   // 16 KB

    const float alpha = p_alpha[0];
    const float beta  = p_beta[0];
    const float phi   = p_phi[0];
    const float gamma = p_gamma[0];
    const float omal  = 1.0f - alpha;
    const float ombe  = 1.0f - beta;
    const float omg   = 1.0f - gamma;

    float l = l0[i];
    float b = b0[i];

    float ring[12];
    {
        const f32x4* s04 = reinterpret_cast<const f32x4*>(s0 + (size_t)i * 12);
        f32x4 sa = s04[0], sb = s04[1], sc = s04[2];
        ring[0] = sa.x; ring[1] = sa.y; ring[2]  = sa.z; ring[3]  = sa.w;
        ring[4] = sb.x; ring[5] = sb.y; ring[6]  = sb.z; ring[7]  = sb.w;
        ring[8] = sc.x; ring[9] = sc.y; ring[10] = sc.z; ring[11] = sc.w;
    }

    // main-chunk tile mapping: flat f4 index f = tid + 64*m over a 64x12 f4
    // tile -> series row r = f/12, time f4-col q = f%12. Precompute swizzled
    // LDS float offsets: r*SROW + ((q ^ (r&7)) << 2).
    int rr[12], qq[12], lo[12];
    #pragma unroll
    for (int m = 0; m < 12; ++m) {
        const int f = tid + SW * m;
        rr[m] = f / 12;
        qq[m] = f - 12 * rr[m];
        lo[m] = rr[m] * SROW + ((qq[m] ^ (rr[m] & 7)) << 2);
    }
    // tail mapping: 64x8 f4 tile -> r = f>>3, q = f&7
    int rt[8], qt[8], lt[8];
    #pragma unroll
    for (int m = 0; m < 8; ++m) {
        const int f = tid + SW * m;
        rt[m] = f >> 3;
        qt[m] = f & 7;
        lt[m] = rt[m] * SROW + ((qt[m] ^ (rt[m] & 7)) << 2);
    }

    const f32x4* x4 = reinterpret_cast<const f32x4*>(x) + (size_t)series0 * PITCH4;
    f32x4*       o4 = reinterpret_cast<f32x4*>(out)     + (size_t)series0 * PITCH4;

    f32x4 vx[12], vn[12], vm[12];

    // prologue: prefetch chunks 0 and 1
    #pragma unroll
    for (int m = 0; m < 12; ++m)
        vx[m] = x4[(size_t)rr[m] * PITCH4 + qq[m]];
    #pragma unroll
    for (int m = 0; m < 12; ++m)
        vn[m] = x4[(size_t)rr[m] * PITCH4 + 12 + qq[m]];

    #pragma unroll 1
    for (int k = 0; k < NCH; ++k) {
        // 1. stage chunk k into LDS, 12 x ds_write_b128 (counted vmcnt on vx)
        #pragma unroll
        for (int m = 0; m < 12; ++m)
            *reinterpret_cast<f32x4*>(&lds_x[lo[m]]) = vx[m];
        CBAR();

        // 2. issue global loads two chunks ahead
        if (k < NCH - 2) {
            #pragma unroll
            for (int m = 0; m < 12; ++m)
                vm[m] = x4[(size_t)rr[m] * PITCH4 + (k + 2) * 12 + qq[m]];
        } else if (k == NCH - 2) {
            #pragma unroll
            for (int m = 0; m < 8; ++m)
                vm[m] = x4[(size_t)rt[m] * PITCH4 + 120 + qt[m]];
        }
        CBAR();

        // 3. compute 48 steps: 12 x (b128 read, 4 steps, b128 write)
        #pragma unroll
        for (int q = 0; q < 12; ++q) {
            const int sl = tid * SROW + ((q ^ t7) << 2);
            const f32x4 xq = *reinterpret_cast<const f32x4*>(&lds_x[sl]);
            f32x4 oq;
            STEPM(xq.x, (4 * q + 0) % 12, (4 * q + 1) % 12, oq.x);
            STEPM(xq.y, (4 * q + 1) % 12, (4 * q + 2) % 12, oq.y);
            STEPM(xq.z, (4 * q + 2) % 12, (4 * q + 3) % 12, oq.z);
            STEPM(xq.w, (4 * q + 3) % 12, (4 * q + 4) % 12, oq.w);
            *reinterpret_cast<f32x4*>(&lds_o[sl]) = oq;
        }
        CBAR();

        // 4. transpose-read outputs (12 x b128) and REGULAR store (A/B vs NT)
        #pragma unroll
        for (int m = 0; m < 12; ++m) {
            const f32x4 o = *reinterpret_cast<const f32x4*>(&lds_o[lo[m]]);
            o4[(size_t)rr[m] * PITCH4 + k * 12 + qq[m]] = o;
        }
        CBAR();

        // rotate prefetch registers
        #pragma unroll
        for (int m = 0; m < 12; ++m) { vx[m] = vn[m]; vn[m] = vm[m]; }
    }

    // ---- tail: steps 480..511 (32 steps, phase 480%12 == 0) ----
    // tail x values were loaded at k == NCH-2 and rotated into vx
    {
        #pragma unroll
        for (int m = 0; m < 8; ++m)
            *reinterpret_cast<f32x4*>(&lds_x[lt[m]]) = vx[m];
        CBAR();
        #pragma unroll
        for (int q = 0; q < 8; ++q) {
            const int sl = tid * SROW + ((q ^ t7) << 2);
            const f32x4 xq = *reinterpret_cast<const f32x4*>(&lds_x[sl]);
            f32x4 oq;
            STEPM(xq.x, (4 * q + 0) % 12, (4 * q + 1) % 12, oq.x);
            STEPM(xq.y, (4 * q + 1) % 12, (4 * q + 2) % 12, oq.y);
            STEPM(xq.z, (4 * q + 2) % 12, (4 * q + 3) % 12, oq.z);
            STEPM(xq.w, (4 * q + 3) % 12, (4 * q + 4) % 12, oq.w);
            *reinterpret_cast<f32x4*>(&lds_o[sl]) = oq;
        }
        CBAR();
        #pragma unroll
        for (int m = 0; m < 8; ++m) {
            const f32x4 o = *reinterpret_cast<const f32x4*>(&lds_o[lt[m]]);
            o4[(size_t)rt[m] * PITCH4 + 120 + qt[m]] = o;
        }
    }
}

extern "C" void kernel_launch(void* const* d_in, const int* in_sizes, int n_in,
                              void* d_out, int out_size, void* d_ws, size_t ws_size,
                              hipStream_t stream)
{
    const float* x       = (const float*)d_in[0];
    const float* p_alpha = (const float*)d_in[1];
    const float* p_beta  = (const float*)d_in[2];
    const float* p_phi   = (const float*)d_in[3];
    const float* p_gamma = (const float*)d_in[4];
    const float* l0      = (const float*)d_in[5];
    const float* b0      = (const float*)d_in[6];
    const float* s0      = (const float*)d_in[7];
    float* out = (float*)d_out;

    const int B = in_sizes[5];          // l0 has B elements
    const int grid = B / SW;            // 1024 blocks of 64 threads

    esrnn_kernel<<<grid, SW, 0, stream>>>(x, p_alpha, p_beta, p_phi, p_gamma,
                                          l0, b0, s0, out);
}

// Round 12
// 47.071 us; speedup vs baseline: 1.3128x; 1.2235x over previous
//
#include <hip/hip_runtime.h>

// ESRNN Holt-Winters, B=65536 series, T=512, period M=12.
// R12: NO x-staging. Reads have within-thread locality (each thread reads its
// own row, 12 consecutive 16B loads per 48-step chunk -> L1 MSHR merge, no
// HBM amplification; proven by R1's read-side counters). x goes straight to
// registers with depth-2 prefetch and counted per-register vmcnt waits.
// LDS is kept ONLY where it's required: transposing outputs so stores are
// full-line coalesced NT (R10 A/B: write path policy is worth 11 us).
// Removes per chunk: 12 staging ds_writes + 12 ds_reads + their waits and
// swizzle VALU (the in-order per-wave DS pipe is a serial resource at our
// hard 1 wave/SIMD occupancy). Everything else = R6 (best known, 46.6 us).

constexpr int TT     = 512;     // timesteps
constexpr int TC     = 48;      // chunk steps
constexpr int NCH    = 10;      // full chunks (480 steps)
constexpr int SW     = 64;      // series per block (one wave)
constexpr int SROW   = 64;      // LDS row stride in floats (16 slots of 16B)
constexpr int PITCH4 = TT / 4;  // global row pitch in float4 units (128)

typedef float f32x4 __attribute__((ext_vector_type(4)));

#define CBAR() asm volatile("" ::: "memory")   // compiler-only barrier

#define STEPM(XV, SH, SN, OV)                                              \
    do {                                                                   \
        const float s_h_ = ring[SH];                                       \
        const float q_   = (XV) * __builtin_amdgcn_rcpf(s_h_);             \
        const float lb_  = fmaf(b, phi, l);                                \
        const float ln_  = fmaf(alpha, q_, omal * lb_);                    \
        const float bphi_ = b * phi;                                       \
        const float bn_  = fmaf(beta, ln_ - l, ombe * bphi_);              \
        const float lb2_ = fmaf(bn_, phi, ln_);                            \
        const float sn_  = fmaf(gamma, (XV) * __builtin_amdgcn_rcpf(lb2_), \
                                omg * s_h_);                               \
        (OV) = lb2_ * ring[SN];                                            \
        ring[SH] = sn_;                                                    \
        l = ln_; b = bn_;                                                  \
    } while (0)

__global__ __launch_bounds__(64) void esrnn_kernel(
    const float* __restrict__ x,
    const float* __restrict__ p_alpha,
    const float* __restrict__ p_beta,
    const float* __restrict__ p_phi,
    const float* __restrict__ p_gamma,
    const float* __restrict__ l0,
    const float* __restrict__ b0,
    const float* __restrict__ s0,
    float* __restrict__ out)
{
    const int tid = threadIdx.x;
    const int t7  = tid & 7;
    const int series0 = blockIdx.x * SW;
    const int i = series0 + tid;

    __shared__ __align__(16) float lds_o[SW * SROW];   // 16 KB (out transpose)

    const float alpha = p_alpha[0];
    const float beta  = p_beta[0];
    const float phi   = p_phi[0];
    const float gamma = p_gamma[0];
    const float omal  = 1.0f - alpha;
    const float ombe  = 1.0f - beta;
    const float omg   = 1.0f - gamma;

    float l = l0[i];
    float b = b0[i];

    float ring[12];
    {
        const f32x4* s04 = reinterpret_cast<const f32x4*>(s0 + (size_t)i * 12);
        f32x4 sa = s04[0], sb = s04[1], sc = s04[2];
        ring[0] = sa.x; ring[1] = sa.y; ring[2]  = sa.z; ring[3]  = sa.w;
        ring[4] = sb.x; ring[5] = sb.y; ring[6]  = sb.z; ring[7]  = sb.w;
        ring[8] = sc.x; ring[9] = sc.y; ring[10] = sc.z; ring[11] = sc.w;
    }

    // out-transpose tile mapping (same as R6): flat f4 index f = tid + 64*m
    // over a 64x12 f4 tile -> series row r = f/12, time f4-col q = f%12.
    // Swizzled LDS float offset: r*SROW + ((q ^ (r&7)) << 2).
    int gxo[12], lo[12];
    #pragma unroll
    for (int m = 0; m < 12; ++m) {
        const int f = tid + SW * m;
        const int r = f / 12;
        const int q = f - 12 * r;
        gxo[m] = r * PITCH4 + q;
        lo[m]  = r * SROW + ((q ^ (r & 7)) << 2);
    }
    // tail mapping: 64x8 f4 tile -> r = f>>3, q = f&7
    int gxT[8], lt[8];
    #pragma unroll
    for (int m = 0; m < 8; ++m) {
        const int f = tid + SW * m;
        const int r = f >> 3;
        const int q = f & 7;
        gxT[m] = r * PITCH4 + 120 + q;
        lt[m]  = r * SROW + ((q ^ (r & 7)) << 2);
    }

    // per-thread x row pointer (direct, no staging)
    const f32x4* xr = reinterpret_cast<const f32x4*>(x) + (size_t)i * PITCH4;
    f32x4*       o4 = reinterpret_cast<f32x4*>(out)     + (size_t)series0 * PITCH4;

    f32x4 vx[12], vn[12], vm[12];

    // prologue: prefetch chunks 0 and 1 (own row, consecutive 16B)
    #pragma unroll
    for (int m = 0; m < 12; ++m) vx[m] = xr[m];
    #pragma unroll
    for (int m = 0; m < 12; ++m) vn[m] = xr[12 + m];

    #pragma unroll 1
    for (int k = 0; k < NCH; ++k) {
        // 1. prefetch two chunks ahead (or the 32-step tail at k==8)
        if (k < NCH - 2) {
            #pragma unroll
            for (int m = 0; m < 12; ++m)
                vm[m] = xr[(k + 2) * 12 + m];
        } else if (k == NCH - 2) {
            #pragma unroll
            for (int m = 0; m < 8; ++m)
                vm[m] = xr[120 + m];
        }
        CBAR();

        // 2. compute 48 steps straight from registers (counted vmcnt waits
        //    on vx only); outputs into swizzled LDS slots (ds_write_b128)
        #pragma unroll
        for (int q = 0; q < 12; ++q) {
            const f32x4 xq = vx[q];
            f32x4 oq;
            STEPM(xq.x, (4 * q + 0) % 12, (4 * q + 1) % 12, oq.x);
            STEPM(xq.y, (4 * q + 1) % 12, (4 * q + 2) % 12, oq.y);
            STEPM(xq.z, (4 * q + 2) % 12, (4 * q + 3) % 12, oq.z);
            STEPM(xq.w, (4 * q + 3) % 12, (4 * q + 4) % 12, oq.w);
            *reinterpret_cast<f32x4*>(&lds_o[tid * SROW + ((q ^ t7) << 2)]) = oq;
        }
        CBAR();

        // 3. transpose-read (12 x ds_read_b128) + coalesced NT store
        #pragma unroll
        for (int m = 0; m < 12; ++m) {
            const f32x4 o = *reinterpret_cast<const f32x4*>(&lds_o[lo[m]]);
            __builtin_nontemporal_store(o, &o4[gxo[m] + k * 12]);
        }
        CBAR();

        // rotate prefetch registers
        #pragma unroll
        for (int m = 0; m < 12; ++m) { vx[m] = vn[m]; vn[m] = vm[m]; }
    }

    // ---- tail: steps 480..511 (32 steps, phase 480%12 == 0) ----
    // tail x values were loaded at k == NCH-2 and rotated into vx[0..7]
    {
        #pragma unroll
        for (int q = 0; q < 8; ++q) {
            const f32x4 xq = vx[q];
            f32x4 oq;
            STEPM(xq.x, (4 * q + 0) % 12, (4 * q + 1) % 12, oq.x);
            STEPM(xq.y, (4 * q + 1) % 12, (4 * q + 2) % 12, oq.y);
            STEPM(xq.z, (4 * q + 2) % 12, (4 * q + 3) % 12, oq.z);
            STEPM(xq.w, (4 * q + 3) % 12, (4 * q + 4) % 12, oq.w);
            *reinterpret_cast<f32x4*>(&lds_o[tid * SROW + ((q ^ t7) << 2)]) = oq;
        }
        CBAR();
        #pragma unroll
        for (int m = 0; m < 8; ++m) {
            const f32x4 o = *reinterpret_cast<const f32x4*>(&lds_o[lt[m]]);
            __builtin_nontemporal_store(o, &o4[gxT[m]]);
        }
    }
}

extern "C" void kernel_launch(void* const* d_in, const int* in_sizes, int n_in,
                              void* d_out, int out_size, void* d_ws, size_t ws_size,
                              hipStream_t stream)
{
    const float* x       = (const float*)d_in[0];
    const float* p_alpha = (const float*)d_in[1];
    const float* p_beta  = (const float*)d_in[2];
    const float* p_phi   = (const float*)d_in[3];
    const float* p_gamma = (const float*)d_in[4];
    const float* l0      = (const float*)d_in[5];
    const float* b0      = (const float*)d_in[6];
    const float* s0      = (const float*)d_in[7];
    float* out = (float*)d_out;

    const int B = in_sizes[5];          // l0 has B elements
    const int grid = B / SW;            // 1024 blocks of 64 threads

    esrnn_kernel<<<grid, SW, 0, stream>>>(x, p_alpha, p_beta, p_phi, p_gamma,
                                          l0, b0, s0, out);
}